// Round 4
// baseline (269.911 us; speedup 1.0000x reference)
//
#include <hip/hip_runtime.h>
#include <stdint.h>

#define NROWS 8192
#define DDIM  256
#define MARGIN_F 0.2f
#define MFMA16 __builtin_amdgcn_mfma_f32_16x16x32_bf16

typedef short  short8  __attribute__((ext_vector_type(8)));
typedef float  floatx4 __attribute__((ext_vector_type(4)));

// Fragment-packed operand layouts (written by prep, read by gemm):
//   dims [rb = row/16 (512)][part hi/lo (2)][kc (8)][rl = row%16 (16)][kw (32)]
// strides (shorts): rb 8192, part 4096, kc 512, rl 32.
// One MFMA fragment (rb, part, kc) = 16 rows x 32 k = 1KB CONTIGUOUS: a
// wave's frag load (lane(l16,quad) -> rl=l16, kw=quad*8..+7) covers exactly
// that block -> every fetched line fully consumed, L1-friendly.
__device__ unsigned short gA[(size_t)NROWS * 512];   // im split hi/lo, packed
__device__ unsigned short gB[(size_t)NROWS * 512];   // s  split hi/lo, packed
__device__ float    g_diag[NROWS];
__device__ unsigned g_rowcnt[NROWS];
__device__ unsigned g_rowkey[NROWS];
__device__ unsigned g_colcnt[NROWS];
__device__ unsigned g_colkey[NROWS];

__device__ __forceinline__ unsigned short f2bf_rne(float x){
    unsigned u = __float_as_uint(x);
    return (unsigned short)((u + 0x7FFFu + ((u >> 16) & 1u)) >> 16);
}
__device__ __forceinline__ float bf2f(unsigned short h){
    return __uint_as_float(((unsigned)h) << 16);
}
// monotone float -> uint key (order-preserving), so atomicMax works on floats
__device__ __forceinline__ unsigned fkey(float f){
    unsigned u = __float_as_uint(f);
    return (u & 0x80000000u) ? ~u : (u | 0x80000000u);
}
__device__ __forceinline__ float kinv(unsigned k){
    unsigned u = (k & 0x80000000u) ? (k ^ 0x80000000u) : ~k;
    return __uint_as_float(u);
}

// One wave per row: fp32 diag dot, hi/lo bf16 split, packed-layout store.
__global__ __launch_bounds__(256) void prep_kernel(const float* __restrict__ im,
                                                   const float* __restrict__ s){
    const int w    = threadIdx.x >> 6;
    const int lane = threadIdx.x & 63;
    const int row  = blockIdx.x * 4 + w;

    const float4 a = ((const float4*)(im + (size_t)row * DDIM))[lane];
    const float4 b = ((const float4*)(s  + (size_t)row * DDIM))[lane];

    float dp = a.x*b.x + a.y*b.y + a.z*b.z + a.w*b.w;
    #pragma unroll
    for (int m = 1; m < 64; m <<= 1) dp += __shfl_xor(dp, m, 64);
    if (lane == 0){
        g_diag[row]   = dp;
        g_rowcnt[row] = 0u; g_rowkey[row] = 0u;
        g_colcnt[row] = 0u; g_colkey[row] = 0u;
    }

    float av[4] = {a.x, a.y, a.z, a.w};
    float bv[4] = {b.x, b.y, b.z, b.w};
    unsigned short ah[4], al[4], bh[4], bl[4];
    #pragma unroll
    for (int i = 0; i < 4; ++i){
        ah[i] = f2bf_rne(av[i]); al[i] = f2bf_rne(av[i] - bf2f(ah[i]));
        bh[i] = f2bf_rne(bv[i]); bl[i] = f2bf_rne(bv[i] - bf2f(bh[i]));
    }
    // lane covers k = lane*4 .. lane*4+3  ->  kc = lane>>3, kw = (lane&7)*4
    const int rb = row >> 4, rl = row & 15;
    const int kc = lane >> 3, kw = (lane & 7) * 4;
    const size_t base = (size_t)rb * 8192 + (size_t)kc * 512 + (size_t)rl * 32 + kw;
    *(ushort4*)&gA[base       ] = make_ushort4(ah[0], ah[1], ah[2], ah[3]);  // part 0
    *(ushort4*)&gA[base + 4096] = make_ushort4(al[0], al[1], al[2], al[3]);  // part 1
    *(ushort4*)&gB[base       ] = make_ushort4(bh[0], bh[1], bh[2], bh[3]);
    *(ushort4*)&gB[base + 4096] = make_ushort4(bl[0], bl[1], bl[2], bl[3]);
}

// 256x256 tile, 8 waves (2Mx4N, 128x64 per wave), 16x16x32 bf16, 3-pass hi/lo.
// R14 vs R10-R13: remove the mechanism class, not the schedule. Four different
// LDS-staged barrier-phase schedules all pinned at 184-199us / 22-24% MfmaUtil
// with SIMDs ~80% idle -> the staging/handoff/lockstep class is the wall.
// Now: NO LDS, NO barriers in the K-loop. Each wave streams its fragments
// global->VGPR (fragment-packed 1KB bursts) and MFMAs independently; the
// compiler's per-register counted vmcnt + natural wave destaggering hide
// latency; intra-block redundant reads (A 4x, B 2x) are served by L1 (32KB =
// exactly one chunk's unique working set). readfirstlane keeps per-wave bases
// uniform (SGPR) to limit address-register pressure.
// Per-element accumulation order identical to R10-R13 (kc 0..7, pass1->2->3,
// mi/nj order unchanged) => absmax 0.
__global__ __launch_bounds__(512, 2) void gemm_stats_kernel(){
    const int tid = threadIdx.x;
    const int bid = blockIdx.x;
    // bid[2:0]->XCD band of bi, bid[4:3]->bi within band, bid[9:5]->bj
    const int bi  = (bid & 7) * 4 + ((bid >> 3) & 3);
    const int bj  = bid >> 5;

    const int w    = tid >> 6, lane = tid & 63;
    const int quad = lane >> 4, l16 = lane & 15;
    const int wr   = __builtin_amdgcn_readfirstlane(w >> 2);   // wave-uniform
    const int wc   = __builtin_amdgcn_readfirstlane(w & 3);

    // per-wave fragment bases: lane offset + wave row/col block.
    // frag(mi): rb = bi*16 + wr*8 + mi ; frag(nj): rb = bj*16 + wc*4 + nj.
    const unsigned short* pA = gA + (size_t)(bi * 16 + wr * 8) * 8192 + l16 * 32 + quad * 8;
    const unsigned short* pB = gB + (size_t)(bj * 16 + wc * 4) * 8192 + l16 * 32 + quad * 8;

    floatx4 acc[8][4] = {};

    #pragma unroll 1
    for (int kc = 0; kc < 8; ++kc){
        const int ko = kc * 512;
        short8 ah[8], al[8], bh[4], bl[4];
        // issue all 24 fragment loads up front (independent); compiler inserts
        // counted vmcnt before each consuming pass.
        #pragma unroll
        for (int mi = 0; mi < 8; ++mi) ah[mi] = *(const short8*)(pA + (size_t)mi * 8192 + ko);
        #pragma unroll
        for (int nj = 0; nj < 4; ++nj) bh[nj] = *(const short8*)(pB + (size_t)nj * 8192 + ko);
        #pragma unroll
        for (int mi = 0; mi < 8; ++mi) al[mi] = *(const short8*)(pA + (size_t)mi * 8192 + 4096 + ko);
        #pragma unroll
        for (int nj = 0; nj < 4; ++nj) bl[nj] = *(const short8*)(pB + (size_t)nj * 8192 + 4096 + ko);

        __builtin_amdgcn_s_setprio(1);
        // pass 1: Ah*Bh
        #pragma unroll
        for (int mi = 0; mi < 8; ++mi)
            #pragma unroll
            for (int nj = 0; nj < 4; ++nj)
                acc[mi][nj] = MFMA16(ah[mi], bh[nj], acc[mi][nj], 0, 0, 0);
        // pass 2: Al*Bh
        #pragma unroll
        for (int mi = 0; mi < 8; ++mi)
            #pragma unroll
            for (int nj = 0; nj < 4; ++nj)
                acc[mi][nj] = MFMA16(al[mi], bh[nj], acc[mi][nj], 0, 0, 0);
        // pass 3: Ah*Bl
        #pragma unroll
        for (int mi = 0; mi < 8; ++mi)
            #pragma unroll
            for (int nj = 0; nj < 4; ++nj)
                acc[mi][nj] = MFMA16(ah[mi], bl[nj], acc[mi][nj], 0, 0, 0);
        __builtin_amdgcn_s_setprio(0);
    }

    // ---- fused stats epilogue ----
    // C/D layout (verified m89/m91): col = lane&15, row = quad*4 + reg.
    // acc[mi][nj]: row = wr*128 + mi*16 + quad*4 + r ; col = wc*64 + nj*16 + l16.
    const int rowbase = bi * 256 + wr * 128;
    const int colbase = bj * 256 + wc * 64;

    // row stats: each lane holds 4 cols (nj); reduce across l16 lanes.
    #pragma unroll
    for (int mi = 0; mi < 8; ++mi){
        #pragma unroll
        for (int r = 0; r < 4; ++r){
            const int gi = rowbase + mi * 16 + quad * 4 + r;
            const float dv = g_diag[gi];
            int cnt = 0; float mx = -3.0e38f;
            #pragma unroll
            for (int nj = 0; nj < 4; ++nj){
                const float v  = acc[mi][nj][r];
                const int   gj = colbase + nj * 16 + l16;
                if (gi != gj){                 // exclude diagonal explicitly
                    cnt += (v < dv) ? 1 : 0;
                    mx = fmaxf(mx, v);
                }
            }
            #pragma unroll
            for (int m = 1; m < 16; m <<= 1){
                cnt += __shfl_xor(cnt, m, 64);
                mx   = fmaxf(mx, __shfl_xor(mx, m, 64));
            }
            if (l16 == 0){
                atomicAdd(&g_rowcnt[gi], (unsigned)cnt);
                atomicMax(&g_rowkey[gi], fkey(mx));
            }
        }
    }
    // col stats: each lane holds 32 rows (mi,r) per nj; reduce across quads.
    #pragma unroll
    for (int nj = 0; nj < 4; ++nj){
        const int gj = colbase + nj * 16 + l16;
        const float dv = g_diag[gj];
        int cnt = 0; float mx = -3.0e38f;
        #pragma unroll
        for (int mi = 0; mi < 8; ++mi){
            #pragma unroll
            for (int r = 0; r < 4; ++r){
                const float v  = acc[mi][nj][r];
                const int   gi = rowbase + mi * 16 + quad * 4 + r;
                if (gi != gj){
                    cnt += (v < dv) ? 1 : 0;
                    mx = fmaxf(mx, v);
                }
            }
        }
        #pragma unroll
        for (int m = 16; m < 64; m <<= 1){
            cnt += __shfl_xor(cnt, m, 64);
            mx   = fmaxf(mx, __shfl_xor(mx, m, 64));
        }
        if (quad == 0){
            atomicAdd(&g_colcnt[gj], (unsigned)cnt);
            atomicMax(&g_colkey[gj], fkey(mx));
        }
    }
}

__global__ __launch_bounds__(256) void finalize_kernel(float* __restrict__ out){
    __shared__ double red[256];
    double acc = 0.0;
    #pragma unroll
    for (int it = 0; it < NROWS / 256; ++it){
        const int i = it * 256 + threadIdx.x;
        const float d  = g_diag[i];
        const float cs  = fmaxf(MARGIN_F + kinv(g_rowkey[i]) - d, 0.0f) * (1.0f / (float)(g_rowcnt[i] + 1u));
        const float cim = fmaxf(MARGIN_F + kinv(g_colkey[i]) - d, 0.0f) * (1.0f / (float)(g_colcnt[i] + 1u));
        acc += (double)cs + (double)cim;
    }
    red[threadIdx.x] = acc;
    __syncthreads();
    for (int s2 = 128; s2 > 0; s2 >>= 1){
        if (threadIdx.x < s2) red[threadIdx.x] += red[threadIdx.x + s2];
        __syncthreads();
    }
    if (threadIdx.x == 0) out[0] = (float)red[0];
}

extern "C" void kernel_launch(void* const* d_in, const int* in_sizes, int n_in,
                              void* d_out, int out_size, void* d_ws, size_t ws_size,
                              hipStream_t stream){
    const float* im = (const float*)d_in[0];
    const float* s  = (const float*)d_in[1];
    float* out = (float*)d_out;

    prep_kernel<<<NROWS / 4, 256, 0, stream>>>(im, s);
    gemm_stats_kernel<<<1024, 512, 0, stream>>>();
    finalize_kernel<<<1, 256, 0, stream>>>(out);
}

// Round 5
// 240.056 us; speedup vs baseline: 1.1244x; 1.1244x over previous
//
#include <hip/hip_runtime.h>
#include <stdint.h>

#define NROWS 8192
#define DDIM  256
#define K2    512          // [hi | lo] packed per row
#define MARGIN_F 0.2f
#define MFMA16 __builtin_amdgcn_mfma_f32_16x16x32_bf16
#define SBAR0() __builtin_amdgcn_sched_barrier(0)

typedef short  short8  __attribute__((ext_vector_type(8)));
typedef float  floatx4 __attribute__((ext_vector_type(4)));

// Static device buffers (avoid depending on ws_size).
__device__ unsigned short gA[(size_t)NROWS * K2];   // im split: [hi | lo]
__device__ unsigned short gB[(size_t)NROWS * K2];   // s  split: [hi | lo]
__device__ float    g_diag[NROWS];
__device__ unsigned g_rowcnt[NROWS];
__device__ unsigned g_rowkey[NROWS];
__device__ unsigned g_colcnt[NROWS];
__device__ unsigned g_colkey[NROWS];

__device__ __forceinline__ unsigned short f2bf_rne(float x){
    unsigned u = __float_as_uint(x);
    return (unsigned short)((u + 0x7FFFu + ((u >> 16) & 1u)) >> 16);
}
__device__ __forceinline__ float bf2f(unsigned short h){
    return __uint_as_float(((unsigned)h) << 16);
}
// monotone float -> uint key (order-preserving), so atomicMax works on floats
__device__ __forceinline__ unsigned fkey(float f){
    unsigned u = __float_as_uint(f);
    return (u & 0x80000000u) ? ~u : (u | 0x80000000u);
}
__device__ __forceinline__ float kinv(unsigned k){
    unsigned u = (k & 0x80000000u) ? (k ^ 0x80000000u) : ~k;
    return __uint_as_float(u);
}

__device__ __forceinline__ void load_lds16(const unsigned short* gptr, void* lptr){
    __builtin_amdgcn_global_load_lds(
        (const __attribute__((address_space(1))) unsigned int*)(uintptr_t)gptr,
        (__attribute__((address_space(3))) unsigned int*)(unsigned)(uintptr_t)lptr,
        16, 0, 0);
}

// One wave per row: fp32 diag dot, hi/lo bf16 split, stats init. (R13 layout)
__global__ __launch_bounds__(256) void prep_kernel(const float* __restrict__ im,
                                                   const float* __restrict__ s){
    const int w    = threadIdx.x >> 6;
    const int lane = threadIdx.x & 63;
    const int row  = blockIdx.x * 4 + w;

    const float4 a = ((const float4*)(im + (size_t)row * DDIM))[lane];
    const float4 b = ((const float4*)(s  + (size_t)row * DDIM))[lane];

    float dp = a.x*b.x + a.y*b.y + a.z*b.z + a.w*b.w;
    #pragma unroll
    for (int m = 1; m < 64; m <<= 1) dp += __shfl_xor(dp, m, 64);
    if (lane == 0){
        g_diag[row]   = dp;
        g_rowcnt[row] = 0u; g_rowkey[row] = 0u;
        g_colcnt[row] = 0u; g_colkey[row] = 0u;
    }

    float av[4] = {a.x, a.y, a.z, a.w};
    float bv[4] = {b.x, b.y, b.z, b.w};
    unsigned short ah[4], al[4], bh[4], bl[4];
    #pragma unroll
    for (int i = 0; i < 4; ++i){
        ah[i] = f2bf_rne(av[i]); al[i] = f2bf_rne(av[i] - bf2f(ah[i]));
        bh[i] = f2bf_rne(bv[i]); bl[i] = f2bf_rne(bv[i] - bf2f(bh[i]));
    }
    const size_t base = (size_t)row * K2 + lane * 4;
    *(ushort4*)&gA[base      ] = make_ushort4(ah[0], ah[1], ah[2], ah[3]);
    *(ushort4*)&gA[base + 256] = make_ushort4(al[0], al[1], al[2], al[3]);
    *(ushort4*)&gB[base      ] = make_ushort4(bh[0], bh[1], bh[2], bh[3]);
    *(ushort4*)&gB[base + 256] = make_ushort4(bl[0], bl[1], bl[2], bl[3]);
}

// Stage one 16KB unit: 256 rows x 32 shorts (one 32-k chunk, hi or lo) of an
// operand tile, 512 threads x 2 x 16B DMA ops. Slot swizzle verified in R13
// (absmax 0, SQ_LDS_BANK_CONFLICT 0): physical 16B slot sp in row r holds
// logical k-slot sp ^ ((r>>1)&3); reader uses sel = (quad ^ ((l16>>1)&3))<<4.
__device__ __forceinline__ void stage_unit256(const unsigned short* __restrict__ Obase,
                                              int c, int hl, unsigned short* sb, int tid){
    #pragma unroll
    for (int q2 = 0; q2 < 2; ++q2){
        const int o  = q2 * 8192 + tid * 16;    // dest byte in 16KB unit
        const int r  = o >> 6;                  // row 0..255 (64B rows)
        const int sp = (o >> 4) & 3;            // physical slot
        const int ql = sp ^ ((r >> 1) & 3);     // logical k-slot
        const size_t goff = (size_t)r * K2 + (size_t)c * 32 + (size_t)hl * 256 + (size_t)ql * 8;
        load_lds16(Obase + goff, (char*)sb + o);
    }
}

// ---- phase helpers ----
#define MFQ(A4, B4, MB) { \
    _Pragma("unroll") \
    for (int i_ = 0; i_ < 4; ++i_){ \
        _Pragma("unroll") \
        for (int nj_ = 0; nj_ < 4; ++nj_) \
            acc[(MB) + i_][nj_] = MFMA16((A4)[i_], (B4)[nj_], acc[(MB) + i_][nj_], 0, 0, 0); \
    } }
#define LDA4(U_, F_, MB) { \
    _Pragma("unroll") \
    for (int i_ = 0; i_ < 4; ++i_) \
        (F_)[i_] = *(const short8*)((const char*)(U_) + aoff + ((MB) + i_) * 1024); }
#define LDB4(U_, F_) { \
    _Pragma("unroll") \
    for (int nj_ = 0; nj_ < 4; ++nj_) \
        (F_)[nj_] = *(const short8*)((const char*)(U_) + boff + nj_ * 1024); }
#define LGKM0() { asm volatile("s_waitcnt lgkmcnt(0)" ::: "memory"); SBAR0(); }
#define BARR()  { SBAR0(); __builtin_amdgcn_s_barrier(); SBAR0(); }

// 256x256 tile, 8 waves (2Mx4N, 128x64/wave), 16x16x32 bf16, 3-pass hi/lo.
// R15 vs R13: faithful m201 fine-phase port. R13's coarse phases (32-MFMA
// blocks, vmcnt right after each stage issue) match m196's REGRESSING coarse
// variant. Now each 32-k chunk = 6 phases {P1a,P1b,P2a,P2b,P3a,P3b}, each:
// stage-issue || 4-8 ds_read_b128 -> lgkmcnt(0)+sched_barrier -> setprio(1)
// 16 MFMA setprio(0) -> barrier. Counted vmcnt only at phase-PAIR ends
// (6/6/4; tail 2/0), each targeting a unit issued a FULL chunk (~6 phases)
// earlier; never 0 in the main loop. Ledger (thread-local FIFO, 2 ops/unit):
// steady state outstanding peaks at 8; VM(6)=retire Al(kc), VM(6)=Bl(kc),
// VM(4)=Ah/Bh(kc+1). Per-element accumulation order unchanged vs R10-R14
// (kc 0..7, pass1->2->3) => absmax 0.
__global__ __launch_bounds__(512, 2) void gemm_stats_kernel(){
    __shared__ unsigned short U[8][256 * 32];   // [0+d]=Ah, [2+d]=Bh, [4+d]=Al, [6+d]=Bl

    const int tid = threadIdx.x;
    const int bid = blockIdx.x;
    // bid[2:0]->XCD band of bi, bid[4:3]->bi within band, bid[9:5]->bj
    const int bi  = (bid & 7) * 4 + ((bid >> 3) & 3);
    const int bj  = bid >> 5;

    const int w    = tid >> 6, lane = tid & 63;
    const int quad = lane >> 4, l16 = lane & 15;
    const int wr   = w >> 2,   wc  = w & 3;
    const int sel  = (quad ^ ((l16 >> 1) & 3)) << 4;   // swizzled 16B slot
    const int aoff = (wr * 128 + l16) * 64 + sel;      // byte off in A units
    const int boff = (wc * 64  + l16) * 64 + sel;      // byte off in B units

    floatx4 acc[8][4] = {};

    const unsigned short* Abase = gA + (size_t)bi * 256 * K2;
    const unsigned short* Bbase = gB + (size_t)bj * 256 * K2;

    // ---- prologue: chunk 0's four units into buffer 0 ----
    stage_unit256(Abase, 0, 0, U[0], tid);
    stage_unit256(Bbase, 0, 0, U[2], tid);
    stage_unit256(Abase, 0, 1, U[4], tid);
    stage_unit256(Bbase, 0, 1, U[6], tid);
    SBAR0();
    asm volatile("s_waitcnt vmcnt(4)" ::: "memory");   // Ah0,Bh0 done
    BARR();

    #pragma unroll 1
    for (int kc = 0; kc < 7; ++kc){
        const int d = kc & 1, e = d ^ 1;
        short8 ah[8], bh[4];
        // ---- P1a: pass1 lower; stage Ah(kc+1) ----
        stage_unit256(Abase, kc + 1, 0, U[0 + e], tid);
        SBAR0();
        LDA4(U[0 + d], &ah[0], 0); LDB4(U[2 + d], bh);
        LGKM0();
        __builtin_amdgcn_s_setprio(1); MFQ(&ah[0], bh, 0); __builtin_amdgcn_s_setprio(0);
        BARR();
        // ---- P1b: pass1 upper; stage Bh(kc+1); VM: Al(kc) ----
        stage_unit256(Bbase, kc + 1, 0, U[2 + e], tid);
        SBAR0();
        LDA4(U[0 + d], &ah[4], 4);
        LGKM0();
        __builtin_amdgcn_s_setprio(1); MFQ(&ah[4], bh, 4); __builtin_amdgcn_s_setprio(0);
        SBAR0();
        asm volatile("s_waitcnt vmcnt(6)" ::: "memory");
        BARR();
        // ---- P2a: pass2 lower; stage Al(kc+1) ----
        {
            stage_unit256(Abase, kc + 1, 1, U[4 + e], tid);
            SBAR0();
            short8 al0[4]; LDA4(U[4 + d], al0, 0);
            LGKM0();
            __builtin_amdgcn_s_setprio(1); MFQ(al0, bh, 0); __builtin_amdgcn_s_setprio(0);
            BARR();
        }
        // ---- P2b: pass2 upper; VM: Bl(kc) ----
        {
            short8 al1[4]; LDA4(U[4 + d], al1, 4);
            LGKM0();
            __builtin_amdgcn_s_setprio(1); MFQ(al1, bh, 4); __builtin_amdgcn_s_setprio(0);
            SBAR0();
            asm volatile("s_waitcnt vmcnt(6)" ::: "memory");
            BARR();
        }
        // ---- P3a: pass3 lower; stage Bl(kc+1) ----
        {
            stage_unit256(Bbase, kc + 1, 1, U[6 + e], tid);
            SBAR0();
            short8 bl[4]; LDB4(U[6 + d], bl);
            LGKM0();
            __builtin_amdgcn_s_setprio(1); MFQ(&ah[0], bl, 0); __builtin_amdgcn_s_setprio(0);
            BARR();
            // ---- P3b: pass3 upper (pure MFMA); VM: Ah/Bh(kc+1) ----
            __builtin_amdgcn_s_setprio(1); MFQ(&ah[4], bl, 4); __builtin_amdgcn_s_setprio(0);
            SBAR0();
            asm volatile("s_waitcnt vmcnt(4)" ::: "memory");
            BARR();
        }
    }
    // ---- tail chunk kc=7 (d=1): no staging; drains 2 -> 0 ----
    {
        short8 ah[8], bh[4];
        // P1a
        LDA4(U[1], &ah[0], 0); LDB4(U[3], bh);
        LGKM0();
        __builtin_amdgcn_s_setprio(1); MFQ(&ah[0], bh, 0); __builtin_amdgcn_s_setprio(0);
        BARR();
        // P1b; VM: Al7
        LDA4(U[1], &ah[4], 4);
        LGKM0();
        __builtin_amdgcn_s_setprio(1); MFQ(&ah[4], bh, 4); __builtin_amdgcn_s_setprio(0);
        SBAR0();
        asm volatile("s_waitcnt vmcnt(2)" ::: "memory");
        BARR();
        // P2a
        {
            short8 al0[4]; LDA4(U[5], al0, 0);
            LGKM0();
            __builtin_amdgcn_s_setprio(1); MFQ(al0, bh, 0); __builtin_amdgcn_s_setprio(0);
            BARR();
        }
        // P2b; VM: Bl7
        {
            short8 al1[4]; LDA4(U[5], al1, 4);
            LGKM0();
            __builtin_amdgcn_s_setprio(1); MFQ(al1, bh, 4); __builtin_amdgcn_s_setprio(0);
            SBAR0();
            asm volatile("s_waitcnt vmcnt(0)" ::: "memory");
            BARR();
        }
        // P3a + P3b
        {
            short8 bl[4]; LDB4(U[7], bl);
            LGKM0();
            __builtin_amdgcn_s_setprio(1); MFQ(&ah[0], bl, 0); MFQ(&ah[4], bl, 4); __builtin_amdgcn_s_setprio(0);
        }
    }

    // ---- fused stats epilogue ----
    // C/D layout (verified m89/m91): col = lane&15, row = quad*4 + reg.
    // acc[mi][nj]: row = wr*128 + mi*16 + quad*4 + r ; col = wc*64 + nj*16 + l16.
    const int rowbase = bi * 256 + wr * 128;
    const int colbase = bj * 256 + wc * 64;

    // row stats: each lane holds 4 cols (nj); reduce across l16 lanes.
    #pragma unroll
    for (int mi = 0; mi < 8; ++mi){
        #pragma unroll
        for (int r = 0; r < 4; ++r){
            const int gi = rowbase + mi * 16 + quad * 4 + r;
            const float dv = g_diag[gi];
            int cnt = 0; float mx = -3.0e38f;
            #pragma unroll
            for (int nj = 0; nj < 4; ++nj){
                const float v  = acc[mi][nj][r];
                const int   gj = colbase + nj * 16 + l16;
                if (gi != gj){                 // exclude diagonal explicitly
                    cnt += (v < dv) ? 1 : 0;
                    mx = fmaxf(mx, v);
                }
            }
            #pragma unroll
            for (int m = 1; m < 16; m <<= 1){
                cnt += __shfl_xor(cnt, m, 64);
                mx   = fmaxf(mx, __shfl_xor(mx, m, 64));
            }
            if (l16 == 0){
                atomicAdd(&g_rowcnt[gi], (unsigned)cnt);
                atomicMax(&g_rowkey[gi], fkey(mx));
            }
        }
    }
    // col stats: each lane holds 32 rows (mi,r) per nj; reduce across quads.
    #pragma unroll
    for (int nj = 0; nj < 4; ++nj){
        const int gj = colbase + nj * 16 + l16;
        const float dv = g_diag[gj];
        int cnt = 0; float mx = -3.0e38f;
        #pragma unroll
        for (int mi = 0; mi < 8; ++mi){
            #pragma unroll
            for (int r = 0; r < 4; ++r){
                const float v  = acc[mi][nj][r];
                const int   gi = rowbase + mi * 16 + quad * 4 + r;
                if (gi != gj){
                    cnt += (v < dv) ? 1 : 0;
                    mx = fmaxf(mx, v);
                }
            }
        }
        #pragma unroll
        for (int m = 16; m < 64; m <<= 1){
            cnt += __shfl_xor(cnt, m, 64);
            mx   = fmaxf(mx, __shfl_xor(mx, m, 64));
        }
        if (quad == 0){
            atomicAdd(&g_colcnt[gj], (unsigned)cnt);
            atomicMax(&g_colkey[gj], fkey(mx));
        }
    }
}

__global__ __launch_bounds__(256) void finalize_kernel(float* __restrict__ out){
    __shared__ double red[256];
    double acc = 0.0;
    #pragma unroll
    for (int it = 0; it < NROWS / 256; ++it){
        const int i = it * 256 + threadIdx.x;
        const float d  = g_diag[i];
        const float cs  = fmaxf(MARGIN_F + kinv(g_rowkey[i]) - d, 0.0f) * (1.0f / (float)(g_rowcnt[i] + 1u));
        const float cim = fmaxf(MARGIN_F + kinv(g_colkey[i]) - d, 0.0f) * (1.0f / (float)(g_colcnt[i] + 1u));
        acc += (double)cs + (double)cim;
    }
    red[threadIdx.x] = acc;
    __syncthreads();
    for (int s2 = 128; s2 > 0; s2 >>= 1){
        if (threadIdx.x < s2) red[threadIdx.x] += red[threadIdx.x + s2];
        __syncthreads();
    }
    if (threadIdx.x == 0) out[0] = (float)red[0];
}

extern "C" void kernel_launch(void* const* d_in, const int* in_sizes, int n_in,
                              void* d_out, int out_size, void* d_ws, size_t ws_size,
                              hipStream_t stream){
    const float* im = (const float*)d_in[0];
    const float* s  = (const float*)d_in[1];
    float* out = (float*)d_out;

    prep_kernel<<<NROWS / 4, 256, 0, stream>>>(im, s);
    gemm_stats_kernel<<<1024, 512, 0, stream>>>();
    finalize_kernel<<<1, 256, 0, stream>>>(out);
}